// Round 2
// baseline (657.347 us; speedup 1.0000x reference)
//
#include <hip/hip_runtime.h>
#include <cfloat>
#include <cstdint>

// Problem constants (match reference)
#define BB 2
#define LL 1024
#define VV 50257
constexpr float BETA     = 0.04f;
constexpr float EPS_LOW  = 0.2f;
constexpr float EPS_HIGH = 0.2f;

// Workspace layout (floats): [0]=mask_sum, [1]=kl_sum, [2]=clip_sum,
// [3..3+BB)=per-seq loss sum, [3+BB..3+2*BB)=per-seq mask len
#define WS_FLOATS (3 + 2 * BB)

// Online-logsumexp combine: (m,s) <- (m,s) ⊕ (om,os)
__device__ __forceinline__ void lse_combine(float& m, float& s, float om, float os) {
    if (om > m) {
        s = s * __expf(m - om) + os;
        m = om;
    } else {
        s = s + os * __expf(om - m);
    }
}

__global__ __launch_bounds__(256) void grpo_row_kernel(
    const float* __restrict__ logits,        // (BB, LL+1, VV)
    const int*   __restrict__ ids,           // (BB, LL)
    const float* __restrict__ advantages,    // (BB,)
    const float* __restrict__ old_logp,      // (BB, LL)
    const float* __restrict__ ref_logp,      // (BB, LL)
    const int*   __restrict__ mask,          // (BB, LL)
    float*       __restrict__ acc)           // WS_FLOATS, pre-zeroed
{
    const int row = blockIdx.x;              // [0, BB*LL)
    const int b   = row >> 10;               // row / LL
    const int t   = row & (LL - 1);          // row % LL
    const float* p = logits + (size_t)b * (LL + 1) * VV + (size_t)t * VV;

    const int tid = threadIdx.x;

    // 16B alignment fixup: rows are only 4B-aligned (VV*4 mod 16 == 4)
    const uintptr_t addr = (uintptr_t)p;
    const int head = (int)(((16 - (addr & 15)) & 15) >> 2);   // 0..3 scalar elems
    const int nvec = (VV - head) >> 2;                        // float4 count
    const int tail_start = head + (nvec << 2);

    float m = -FLT_MAX, s = 0.0f;

    // head scalars (<=3)
    for (int i = tid; i < head; i += 256) {
        float x = p[i];
        if (x > m) { s *= __expf(m - x); m = x; }
        s += __expf(x - m);
    }
    // tail scalars (<=3)
    for (int i = tail_start + tid; i < VV; i += 256) {
        float x = p[i];
        if (x > m) { s *= __expf(m - x); m = x; }
        s += __expf(x - m);
    }

    // main vectorized stream: ~49 float4 per thread
    const float4* pv = (const float4*)(p + head);
    for (int i = tid; i < nvec; i += 256) {
        float4 x = pv[i];
        float mx = fmaxf(fmaxf(x.x, x.y), fmaxf(x.z, x.w));
        if (mx > m) { s *= __expf(m - mx); m = mx; }
        s += __expf(x.x - m) + __expf(x.y - m) + __expf(x.z - m) + __expf(x.w - m);
    }

    // wave (64-lane) butterfly reduction of (m, s)
    #pragma unroll
    for (int off = 32; off > 0; off >>= 1) {
        float om = __shfl_down(m, off);
        float os = __shfl_down(s, off);
        lse_combine(m, s, om, os);
    }

    // cross-wave via LDS (4 waves / block)
    __shared__ float sm[4], ss[4];
    const int lane = tid & 63, wave = tid >> 6;
    if (lane == 0) { sm[wave] = m; ss[wave] = s; }
    __syncthreads();

    if (tid == 0) {
        m = sm[0]; s = ss[0];
        #pragma unroll
        for (int w = 1; w < 4; w++) lse_combine(m, s, sm[w], ss[w]);

        const float lse  = m + __logf(s);
        const int   id   = ids[row];
        const float tok  = p[id];                 // L2-hot re-read
        const float logp = tok - lse;

        const float c1  = __expf(logp - old_logp[row]);
        const float c2  = fminf(fmaxf(c1, 1.0f - EPS_LOW), 1.0f + EPS_HIGH);
        const float adv = advantages[b];
        const float l1  = c1 * adv;
        const float l2  = c2 * adv;
        float ptl = -fminf(l1, l2);

        const float diff = ref_logp[row] - logp;
        const float kl   = __expf(diff) - diff - 1.0f;
        ptl += BETA * kl;

        const float mk = (float)mask[row];
        const bool clipped = ((c1 < 1.0f - EPS_LOW) && (adv < 0.0f)) ||
                             ((c1 > 1.0f + EPS_HIGH) && (adv > 0.0f));

        atomicAdd(&acc[0], mk);
        atomicAdd(&acc[1], kl * mk);
        atomicAdd(&acc[2], (clipped ? 1.0f : 0.0f) * mk);
        atomicAdd(&acc[3 + b], ptl * mk);
        atomicAdd(&acc[3 + BB + b], mk);
    }
}

__global__ void grpo_finalize_kernel(const float* __restrict__ acc,
                                     float* __restrict__ out) {
    if (threadIdx.x == 0 && blockIdx.x == 0) {
        const float mask_sum   = fmaxf(acc[0], 1.0f);
        const float kl_mean    = acc[1] / mask_sum;
        const float clip_ratio = acc[2] / mask_sum;
        float loss = 0.0f;
        #pragma unroll
        for (int b = 0; b < BB; b++) {
            loss += acc[3 + b] / fmaxf(acc[3 + BB + b], 1.0f);
        }
        out[0] = loss / (float)BB;
        out[1] = kl_mean;
        out[2] = clip_ratio;
    }
}

extern "C" void kernel_launch(void* const* d_in, const int* in_sizes, int n_in,
                              void* d_out, int out_size, void* d_ws, size_t ws_size,
                              hipStream_t stream) {
    const float* logits     = (const float*)d_in[0];
    const int*   ids        = (const int*)  d_in[1];
    const float* advantages = (const float*)d_in[2];
    const float* old_logp   = (const float*)d_in[3];
    const float* ref_logp   = (const float*)d_in[4];
    const int*   mask       = (const int*)  d_in[5];
    float* out = (float*)d_out;
    float* acc = (float*)d_ws;

    hipMemsetAsync(acc, 0, WS_FLOATS * sizeof(float), stream);
    grpo_row_kernel<<<BB * LL, 256, 0, stream>>>(
        logits, ids, advantages, old_logp, ref_logp, mask, acc);
    grpo_finalize_kernel<<<1, 64, 0, stream>>>(acc, out);
}

// Round 3
// 544.922 us; speedup vs baseline: 1.2063x; 1.2063x over previous
//
#include <hip/hip_runtime.h>
#include <cfloat>
#include <cstdint>

// Problem constants (match reference)
#define BB 2
#define LL 1024
#define VV 50257
constexpr float BETA     = 0.04f;
constexpr float EPS_LOW  = 0.2f;
constexpr float EPS_HIGH = 0.2f;

// Online-logsumexp combine: (m,s) <- (m,s) ⊕ (om,os)
__device__ __forceinline__ void lse_combine(float& m, float& s, float om, float os) {
    if (om > m) {
        s = s * __expf(m - om) + os;
        m = om;
    } else {
        s = s + os * __expf(om - m);
    }
}

// Pass 1: one block per (b,t) row. Stream the V-row once (float4, online LSE),
// write logp[row] to workspace. No atomics, no memset dependency.
__global__ __launch_bounds__(256) void grpo_row_kernel(
    const float* __restrict__ logits,        // (BB, LL+1, VV)
    const int*   __restrict__ ids,           // (BB, LL)
    float*       __restrict__ logp_out)      // (BB*LL,) in d_ws
{
    const int row = blockIdx.x;              // [0, BB*LL)
    const int b   = row >> 10;               // row / LL
    const int t   = row & (LL - 1);          // row % LL
    const float* p = logits + (size_t)b * (LL + 1) * VV + (size_t)t * VV;

    const int tid = threadIdx.x;

    // 16B alignment fixup: rows are only 4B-aligned (VV*4 mod 16 == 4)
    const uintptr_t addr = (uintptr_t)p;
    const int head = (int)(((16 - (addr & 15)) & 15) >> 2);   // 0..3 scalar elems
    const int nvec = (VV - head) >> 2;                        // float4 count
    const int tail_start = head + (nvec << 2);

    float m = -FLT_MAX, s = 0.0f;

    // head scalars (<=3)
    for (int i = tid; i < head; i += 256) {
        float x = p[i];
        if (x > m) { s *= __expf(m - x); m = x; }
        s += __expf(x - m);
    }
    // tail scalars (<=3)
    for (int i = tail_start + tid; i < VV; i += 256) {
        float x = p[i];
        if (x > m) { s *= __expf(m - x); m = x; }
        s += __expf(x - m);
    }

    // main vectorized stream: ~49 float4 per thread, coalesced 1KB/wave-instr
    const float4* pv = (const float4*)(p + head);
    for (int i = tid; i < nvec; i += 256) {
        float4 x = pv[i];
        float mx = fmaxf(fmaxf(x.x, x.y), fmaxf(x.z, x.w));
        if (mx > m) { s *= __expf(m - mx); m = mx; }
        s += __expf(x.x - m) + __expf(x.y - m) + __expf(x.z - m) + __expf(x.w - m);
    }

    // wave (64-lane) butterfly reduction of (m, s)
    #pragma unroll
    for (int off = 32; off > 0; off >>= 1) {
        float om = __shfl_down(m, off);
        float os = __shfl_down(s, off);
        lse_combine(m, s, om, os);
    }

    // cross-wave via LDS (4 waves / block)
    __shared__ float sm[4], ss[4];
    const int lane = tid & 63, wave = tid >> 6;
    if (lane == 0) { sm[wave] = m; ss[wave] = s; }
    __syncthreads();

    if (tid == 0) {
        m = sm[0]; s = ss[0];
        #pragma unroll
        for (int w = 1; w < 4; w++) lse_combine(m, s, sm[w], ss[w]);

        const float lse = m + __logf(s);
        const float tok = p[ids[row]];            // L2-hot re-read
        logp_out[row] = tok - lse;
    }
}

// Pass 2: single block. Coalesced reads of logp + side arrays, full GRPO
// epilogue, deterministic tree reduction, 3 scalar outputs.
__global__ __launch_bounds__(256) void grpo_finalize_kernel(
    const float* __restrict__ logp_arr,      // (BB*LL,) from d_ws
    const float* __restrict__ advantages,    // (BB,)
    const float* __restrict__ old_logp,      // (BB, LL)
    const float* __restrict__ ref_logp,      // (BB, LL)
    const int*   __restrict__ mask,          // (BB, LL)
    float*       __restrict__ out)           // [loss, kl_mean, clip_ratio]
{
    const int tid = threadIdx.x;

    float kl_sum = 0.0f, clip_sum = 0.0f;
    float loss_sum[BB] = {0.0f, 0.0f};
    float len_sum[BB]  = {0.0f, 0.0f};

    for (int row = tid; row < BB * LL; row += 256) {
        const int   b    = row >> 10;
        const float logp = logp_arr[row];
        const float adv  = advantages[b];

        const float c1 = __expf(logp - old_logp[row]);
        const float c2 = fminf(fmaxf(c1, 1.0f - EPS_LOW), 1.0f + EPS_HIGH);
        const float l1 = c1 * adv;
        const float l2 = c2 * adv;

        const float diff = ref_logp[row] - logp;
        const float kl   = __expf(diff) - diff - 1.0f;
        const float ptl  = -fminf(l1, l2) + BETA * kl;

        const float mk = (float)mask[row];
        const bool clipped = ((c1 < 1.0f - EPS_LOW) && (adv < 0.0f)) ||
                             ((c1 > 1.0f + EPS_HIGH) && (adv > 0.0f));

        kl_sum       += kl * mk;
        clip_sum     += clipped ? mk : 0.0f;
        loss_sum[b]  += ptl * mk;
        len_sum[b]   += mk;
    }

    // 6-value reduction: wave butterfly, then LDS across the 4 waves
    #pragma unroll
    for (int off = 32; off > 0; off >>= 1) {
        kl_sum      += __shfl_down(kl_sum, off);
        clip_sum    += __shfl_down(clip_sum, off);
        loss_sum[0] += __shfl_down(loss_sum[0], off);
        loss_sum[1] += __shfl_down(loss_sum[1], off);
        len_sum[0]  += __shfl_down(len_sum[0], off);
        len_sum[1]  += __shfl_down(len_sum[1], off);
    }

    __shared__ float red[4][6];
    const int lane = tid & 63, wave = tid >> 6;
    if (lane == 0) {
        red[wave][0] = kl_sum;      red[wave][1] = clip_sum;
        red[wave][2] = loss_sum[0]; red[wave][3] = loss_sum[1];
        red[wave][4] = len_sum[0];  red[wave][5] = len_sum[1];
    }
    __syncthreads();

    if (tid == 0) {
        float v[6];
        #pragma unroll
        for (int j = 0; j < 6; j++)
            v[j] = red[0][j] + red[1][j] + red[2][j] + red[3][j];

        const float mask_sum = fmaxf(v[4] + v[5], 1.0f);
        const float loss0 = v[2] / fmaxf(v[4], 1.0f);
        const float loss1 = v[3] / fmaxf(v[5], 1.0f);

        out[0] = 0.5f * (loss0 + loss1);
        out[1] = v[0] / mask_sum;
        out[2] = v[1] / mask_sum;
    }
}

extern "C" void kernel_launch(void* const* d_in, const int* in_sizes, int n_in,
                              void* d_out, int out_size, void* d_ws, size_t ws_size,
                              hipStream_t stream) {
    const float* logits     = (const float*)d_in[0];
    const int*   ids        = (const int*)  d_in[1];
    const float* advantages = (const float*)d_in[2];
    const float* old_logp   = (const float*)d_in[3];
    const float* ref_logp   = (const float*)d_in[4];
    const int*   mask       = (const int*)  d_in[5];
    float* out  = (float*)d_out;
    float* logp = (float*)d_ws;   // BB*LL floats

    grpo_row_kernel<<<BB * LL, 256, 0, stream>>>(logits, ids, logp);
    grpo_finalize_kernel<<<1, 256, 0, stream>>>(
        logp, advantages, old_logp, ref_logp, mask, out);
}

// Round 5
// 515.153 us; speedup vs baseline: 1.2760x; 1.0578x over previous
//
#include <hip/hip_runtime.h>
#include <cfloat>
#include <cstdint>

// Problem constants (match reference)
#define BB 2
#define LL 1024
#define VV 50257
constexpr float BETA     = 0.04f;
constexpr float EPS_LOW  = 0.2f;
constexpr float EPS_HIGH = 0.2f;

// Native clang vector type — required by __builtin_nontemporal_load
// (HIP_vector_type float4 is a struct and is rejected).
typedef float vf4 __attribute__((ext_vector_type(4)));

// Online-logsumexp combine: (m,s) <- (m,s) ⊕ (om,os)
__device__ __forceinline__ void lse_combine(float& m, float& s, float om, float os) {
    if (om > m) {
        s = s * __expf(m - om) + os;
        m = om;
    } else {
        s = s + os * __expf(om - m);
    }
}

__device__ __forceinline__ void lse_accum4(float& m, float& s, vf4 x) {
    float mx = fmaxf(fmaxf(x.x, x.y), fmaxf(x.z, x.w));
    if (mx > m) { s *= __expf(m - mx); m = mx; }
    s += __expf(x.x - m) + __expf(x.y - m) + __expf(x.z - m) + __expf(x.w - m);
}

// Pass 1: one block per (b,t) row. Stream the V-row once (nontemporal float4,
// online LSE with 2 independent accumulator chains), capture the token logit
// in-stream, write logp[row] to workspace.
__global__ __launch_bounds__(256) void grpo_row_kernel(
    const float* __restrict__ logits,        // (BB, LL+1, VV)
    const int*   __restrict__ ids,           // (BB, LL)
    float*       __restrict__ logp_out)      // (BB*LL,) in d_ws
{
    const int row = blockIdx.x;              // [0, BB*LL)
    const int b   = row >> 10;               // row / LL
    const int t   = row & (LL - 1);          // row % LL
    const float* p = logits + (size_t)b * (LL + 1) * VV + (size_t)t * VV;

    const int tid = threadIdx.x;
    const int id  = ids[row];                // token index, known up-front

    // 16B alignment fixup: rows are only 4B-aligned (VV*4 mod 16 == 4)
    const uintptr_t addr = (uintptr_t)p;
    const int head = (int)(((16 - (addr & 15)) & 15) >> 2);   // 0..3 scalar elems
    const int nvec = (VV - head) >> 2;                        // float4 count
    const int tail_start = head + (nvec << 2);

    // which float4 (and component) holds the token logit
    const int tok_vec  = (id >= head && id < tail_start) ? ((id - head) >> 2) : -1;
    const int tok_comp = (id - head) & 3;

    __shared__ float stok;

    float m0 = -FLT_MAX, s0 = 0.0f;
    float m1 = -FLT_MAX, s1 = 0.0f;

    // head scalars (<=3)
    for (int i = tid; i < head; i += 256) {
        float x = p[i];
        if (i == id) stok = x;
        if (x > m0) { s0 *= __expf(m0 - x); m0 = x; }
        s0 += __expf(x - m0);
    }
    // tail scalars (<=3)
    for (int i = tail_start + tid; i < VV; i += 256) {
        float x = p[i];
        if (i == id) stok = x;
        if (x > m0) { s0 *= __expf(m0 - x); m0 = x; }
        s0 += __expf(x - m0);
    }

    // main stream: 2 independent float4 chains (ILP), nontemporal (no reuse)
    const vf4* pv = (const vf4*)(p + head);
    int i = tid;
    for (; i + 256 < nvec; i += 512) {
        vf4 x = __builtin_nontemporal_load(pv + i);
        vf4 y = __builtin_nontemporal_load(pv + i + 256);
        if (i == tok_vec)       stok = x[tok_comp];
        if (i + 256 == tok_vec) stok = y[tok_comp];
        lse_accum4(m0, s0, x);
        lse_accum4(m1, s1, y);
    }
    if (i < nvec) {
        vf4 x = __builtin_nontemporal_load(pv + i);
        if (i == tok_vec) stok = x[tok_comp];
        lse_accum4(m0, s0, x);
    }

    // merge the two chains, then wave (64-lane) butterfly reduction
    lse_combine(m0, s0, m1, s1);
    #pragma unroll
    for (int off = 32; off > 0; off >>= 1) {
        float om = __shfl_down(m0, off);
        float os = __shfl_down(s0, off);
        lse_combine(m0, s0, om, os);
    }

    // cross-wave via LDS (4 waves / block)
    __shared__ float sm[4], ss[4];
    const int lane = tid & 63, wave = tid >> 6;
    if (lane == 0) { sm[wave] = m0; ss[wave] = s0; }
    __syncthreads();

    if (tid == 0) {
        float m = sm[0], s = ss[0];
        #pragma unroll
        for (int w = 1; w < 4; w++) lse_combine(m, s, sm[w], ss[w]);
        logp_out[row] = stok - (m + __logf(s));
    }
}

// Pass 2: single block. Coalesced reads of logp + side arrays, full GRPO
// epilogue, deterministic tree reduction, 3 scalar outputs.
__global__ __launch_bounds__(256) void grpo_finalize_kernel(
    const float* __restrict__ logp_arr,      // (BB*LL,) from d_ws
    const float* __restrict__ advantages,    // (BB,)
    const float* __restrict__ old_logp,      // (BB, LL)
    const float* __restrict__ ref_logp,      // (BB, LL)
    const int*   __restrict__ mask,          // (BB, LL)
    float*       __restrict__ out)           // [loss, kl_mean, clip_ratio]
{
    const int tid = threadIdx.x;

    float kl_sum = 0.0f, clip_sum = 0.0f;
    float loss_sum[BB] = {0.0f, 0.0f};
    float len_sum[BB]  = {0.0f, 0.0f};

    for (int row = tid; row < BB * LL; row += 256) {
        const int   b    = row >> 10;
        const float logp = logp_arr[row];
        const float adv  = advantages[b];

        const float c1 = __expf(logp - old_logp[row]);
        const float c2 = fminf(fmaxf(c1, 1.0f - EPS_LOW), 1.0f + EPS_HIGH);
        const float l1 = c1 * adv;
        const float l2 = c2 * adv;

        const float diff = ref_logp[row] - logp;
        const float kl   = __expf(diff) - diff - 1.0f;
        const float ptl  = -fminf(l1, l2) + BETA * kl;

        const float mk = (float)mask[row];
        const bool clipped = ((c1 < 1.0f - EPS_LOW) && (adv < 0.0f)) ||
                             ((c1 > 1.0f + EPS_HIGH) && (adv > 0.0f));

        kl_sum       += kl * mk;
        clip_sum     += clipped ? mk : 0.0f;
        loss_sum[b]  += ptl * mk;
        len_sum[b]   += mk;
    }

    // 6-value reduction: wave butterfly, then LDS across the 4 waves
    #pragma unroll
    for (int off = 32; off > 0; off >>= 1) {
        kl_sum      += __shfl_down(kl_sum, off);
        clip_sum    += __shfl_down(clip_sum, off);
        loss_sum[0] += __shfl_down(loss_sum[0], off);
        loss_sum[1] += __shfl_down(loss_sum[1], off);
        len_sum[0]  += __shfl_down(len_sum[0], off);
        len_sum[1]  += __shfl_down(len_sum[1], off);
    }

    __shared__ float red[4][6];
    const int lane = tid & 63, wave = tid >> 6;
    if (lane == 0) {
        red[wave][0] = kl_sum;      red[wave][1] = clip_sum;
        red[wave][2] = loss_sum[0]; red[wave][3] = loss_sum[1];
        red[wave][4] = len_sum[0];  red[wave][5] = len_sum[1];
    }
    __syncthreads();

    if (tid == 0) {
        float v[6];
        #pragma unroll
        for (int j = 0; j < 6; j++)
            v[j] = red[0][j] + red[1][j] + red[2][j] + red[3][j];

        const float mask_sum = fmaxf(v[4] + v[5], 1.0f);
        const float loss0 = v[2] / fmaxf(v[4], 1.0f);
        const float loss1 = v[3] / fmaxf(v[5], 1.0f);

        out[0] = 0.5f * (loss0 + loss1);
        out[1] = v[0] / mask_sum;
        out[2] = v[1] / mask_sum;
    }
}

extern "C" void kernel_launch(void* const* d_in, const int* in_sizes, int n_in,
                              void* d_out, int out_size, void* d_ws, size_t ws_size,
                              hipStream_t stream) {
    const float* logits     = (const float*)d_in[0];
    const int*   ids        = (const int*)  d_in[1];
    const float* advantages = (const float*)d_in[2];
    const float* old_logp   = (const float*)d_in[3];
    const float* ref_logp   = (const float*)d_in[4];
    const int*   mask       = (const int*)  d_in[5];
    float* out  = (float*)d_out;
    float* logp = (float*)d_ws;   // BB*LL floats

    grpo_row_kernel<<<BB * LL, 256, 0, stream>>>(logits, ids, logp);
    grpo_finalize_kernel<<<1, 256, 0, stream>>>(
        logp, advantages, old_logp, ref_logp, mask, out);
}